// Round 17
// baseline (167.830 us; speedup 1.0000x reference)
//
#include <hip/hip_runtime.h>
#include <math.h>
#include <stdint.h>

#define K_DIM 8192     // S*DIM
#define D_DIM 2048
#define M_ROWS 8192
#define N_W 32         // W columns (only 24 used in H)
#define NC 24
#define KSPLIT 8       // grid.y; 1024 k per block
#define ROWS 16        // rows per block = one MFMA tile
#define THR 64         // ONE wave per block
#define CCOL 128       // cols per chunk (16 rows x 512B runs = 8KB)
#define NCH 8          // chunks per block (8 x 128 = 1024 k)
#define KSC 4          // ksteps (32 k) per chunk

typedef short bf16x8 __attribute__((ext_vector_type(8)));
typedef float f32x4 __attribute__((ext_vector_type(4)));
union U32x4 { uint32_t u[4]; bf16x8 v; };

typedef const uint32_t __attribute__((address_space(1)))* gas_ptr;
typedef uint32_t __attribute__((address_space(3)))* las_ptr;

// wfrag (u16, W rne-bf16 hi-only): [ks(256)][tile(2)][lane(64)][e(8)] = 512 KB.
#define WFI(ks, tile) (((ks) * 2 + (tile)) * 64)   // bf16x8 units

// ---------------------------------------------------------------------------
// Kernel 0: prepack W -> rne bf16 B-fragments (once).
// k-map matches A-frag map: lane=((k&31)>>3)*16+(n&15), e=k&7 (same perm on
// both MFMA operands so it cancels; only C/D layout matters).
// ---------------------------------------------------------------------------
__global__ __launch_bounds__(256) void mhc_prepack_kernel(
    const float* __restrict__ W, unsigned short* __restrict__ wfrag)
{
    const int idx = blockIdx.x * 256 + threadIdx.x;   // 0 .. 262143
    const int k = idx >> 5, n = idx & 31;
    const float w = W[(size_t)k * N_W + n];
    const uint32_t u = __float_as_uint(w);
    const uint32_t r = u + 0x7FFFu + ((u >> 16) & 1u);   // round-nearest-even

    const int ks = k >> 5, kk = k & 31;
    const int lane = ((kk >> 3) << 4) | (n & 15);
    const int e = kk & 7;
    const int tile = n >> 4;
    wfrag[((size_t)WFI(ks, tile) + lane) * 8 + e] = (unsigned short)(r >> 16);
}

// ---------------------------------------------------------------------------
// Kernel 1: partial H via MFMA, H = Xhi@W + Xlo@W.
// R16's two fixes with CORRECTED gll geometry (R16 wrote 1KB/row into 512B
// slots -> LDS OOB abort):
//  - one global_load_lds stages TWO rows: lanes 0-31 read row 2g's 512B run,
//    lanes 32-63 read row 2g+1's (per-lane global source); linear LDS dest
//    covers both adjacent row slots. 8 gll per 8KB chunk.
//  - bank-conflict fix (rule #21): global source slot pre-XOR'd with row&7,
//    ds_read applies the same XOR -> 16 lanes spread over 8 four-bank groups
//    (2-way = free). Coalescing kept (same 512B line set per run).
//  - occupancy: 2x8KB LDS, 1 wave/block -> 10 blocks/CU; 4096 blocks.
// Per chunk: 8 B-loads (L2) -> 8 gll (next chunk) -> vmcnt(8) -> 4 ksteps
// x {2 swizzled ds_read_b128, pack, 4 MFMA}. No barriers, no atomics.
// C/D: D[row=(l>>4)*4+reg][col=l&15]  [HW-verified].
// ---------------------------------------------------------------------------
__global__ __launch_bounds__(THR) void mhc_gemm_kernel(
    const float* __restrict__ X, const unsigned short* __restrict__ wfrag,
    float* __restrict__ part)
{
    __shared__ __align__(16) float Xl[2][ROWS * CCOL];   // 2 x 8 KB
    const int l = threadIdx.x;
    const int rowbase = blockIdx.x * ROWS;
    const int colbase = blockIdx.y * (K_DIM / KSPLIT);
    const int ks00 = blockIdx.y * (K_DIM / KSPLIT / 32);

    const bf16x8* __restrict__ wf = reinterpret_cast<const bf16x8*>(wfrag);

    f32x4 c0 = {0.f, 0.f, 0.f, 0.f};
    f32x4 c1 = {0.f, 0.f, 0.f, 0.f};

    // per-lane staging source offsets: half-wave h = l>>5 handles row 2g+h
    const int hs = l >> 5;                 // 0 or 1
    const int sl = l & 31;                 // slot within the row's 32 slots

    // ---- issue chunk 0's X loads (8 gll x 2 rows) ----
#pragma unroll
    for (int g = 0; g < 8; ++g) {
        const int r2 = 2 * g + hs;
        const float* src = X + (size_t)(rowbase + r2) * K_DIM + colbase
                           + ((sl ^ (r2 & 7)) << 2);
        __builtin_amdgcn_global_load_lds((gas_ptr)src,
                                         (las_ptr)&Xl[0][2 * g * CCOL], 16, 0, 0);
    }

#pragma unroll
    for (int c = 0; c < NCH; ++c) {
        // ---- B-loads for chunk c (before next-chunk X: vmcnt order) ----
        bf16x8 b0[KSC], b1[KSC];
#pragma unroll
        for (int s = 0; s < KSC; ++s) {
            const int ks = ks00 + c * KSC + s;
            b0[s] = wf[WFI(ks, 0) + l];
            b1[s] = wf[WFI(ks, 1) + l];
        }
        __builtin_amdgcn_sched_barrier(0);

        // ---- issue chunk c+1's X loads into the other buffer ----
        if (c + 1 < NCH) {
#pragma unroll
            for (int g = 0; g < 8; ++g) {
                const int r2 = 2 * g + hs;
                const float* src = X + (size_t)(rowbase + r2) * K_DIM + colbase
                                   + (c + 1) * CCOL + ((sl ^ (r2 & 7)) << 2);
                __builtin_amdgcn_global_load_lds(
                    (gas_ptr)src, (las_ptr)&Xl[(c + 1) & 1][2 * g * CCOL],
                    16, 0, 0);
            }
            __builtin_amdgcn_sched_barrier(0);
            asm volatile("s_waitcnt vmcnt(8)" ::: "memory");
        } else {
            __builtin_amdgcn_sched_barrier(0);
            asm volatile("s_waitcnt vmcnt(0)" ::: "memory");
        }
        __builtin_amdgcn_sched_barrier(0);   // rule #18: fence ds_read hoisting

        // ---- compute chunk c: 4 ksteps, swizzled A-frag reads ----
        const int ar = l & 15;               // A row
        const int q = ar & 7;                // row XOR key
        const float* xrow = &Xl[c & 1][ar * CCOL];
#pragma unroll
        for (int s = 0; s < KSC; ++s) {
            const int slot = s * 8 + ((l >> 4) << 1);   // logical 16B slot
            const float4 xa = *reinterpret_cast<const float4*>(
                xrow + ((slot ^ q) << 2));
            const float4 xb = *reinterpret_cast<const float4*>(
                xrow + (((slot + 1) ^ q) << 2));
            float xs[8];
            xs[0] = xa.x; xs[1] = xa.y; xs[2] = xa.z; xs[3] = xa.w;
            xs[4] = xb.x; xs[5] = xb.y; xs[6] = xb.z; xs[7] = xb.w;

            U32x4 ah, al;
#pragma unroll
            for (int p = 0; p < 4; ++p) {
                const uint32_t u0 = __float_as_uint(xs[2 * p]);
                const uint32_t u1 = __float_as_uint(xs[2 * p + 1]);
                const float h0 = __uint_as_float(u0 & 0xFFFF0000u);
                const float h1 = __uint_as_float(u1 & 0xFFFF0000u);
                const uint32_t r0 = __float_as_uint(xs[2 * p] - h0);
                const uint32_t r1 = __float_as_uint(xs[2 * p + 1] - h1);
                ah.u[p] = (u1 & 0xFFFF0000u) | (u0 >> 16);
                al.u[p] = (r1 & 0xFFFF0000u) | (r0 >> 16);
            }

            c0 = __builtin_amdgcn_mfma_f32_16x16x32_bf16(ah.v, b0[s], c0, 0, 0, 0);
            c0 = __builtin_amdgcn_mfma_f32_16x16x32_bf16(al.v, b0[s], c0, 0, 0, 0);
            c1 = __builtin_amdgcn_mfma_f32_16x16x32_bf16(ah.v, b1[s], c1, 0, 0, 0);
            c1 = __builtin_amdgcn_mfma_f32_16x16x32_bf16(al.v, b1[s], c1, 0, 0, 0);
        }
    }

    // ---- non-atomic partial store: part[by][row][col] ----
    float* prow = part + ((size_t)blockIdx.y * M_ROWS + rowbase) * NC;
    const int drow0 = (l >> 4) << 2;
    const int col = l & 15;
#pragma unroll
    for (int r = 0; r < 4; ++r)
        prow[(drow0 + r) * NC + col] = c0[r];
    if (col < 8) {
#pragma unroll
        for (int r = 0; r < 4; ++r)
            prow[(drow0 + r) * NC + 16 + col] = c1[r];
    }
}

// ---------------------------------------------------------------------------
// Kernel 2: reduce partials + params (transform + sinkhorn) + apply.
// One block per row.
// ---------------------------------------------------------------------------
__global__ __launch_bounds__(256) void mhc_apply_kernel(
    const float* __restrict__ X, const float* __restrict__ part,
    const float* __restrict__ ab, float* __restrict__ out)
{
    __shared__ float pbuf[NC];
    const int row = blockIdx.x;
    const int t = threadIdx.x;

    if (t < 64) {
        const int lane = t;
        float pl = 0.f;
        if (lane < NC) {
#pragma unroll
            for (int j = 0; j < KSPLIT; ++j)
                pl += part[((size_t)j * M_ROWS + row) * NC + lane];
        }
        const float bias  = (lane < NC) ? ab[lane] : 0.f;
        const float scale = ab[(lane < 16) ? 24 : ((lane < 20) ? 25 : 26)];

        float vout;
        if (lane < 16) {
            vout = __expf(fmaf(scale, pl, bias));                 // exp(a_res*H+b)
        } else {
            vout = fmaf(scale, 1.f / (1.f + __expf(-pl)), bias);  // a*sigmoid(H)+b
        }

        // Sinkhorn on lanes 0..15: lane = s*4 + i.
        float p = vout;
        for (int it = 0; it < 20; ++it) {
            float rs = p + __shfl_xor(p, 1);
            rs += __shfl_xor(rs, 2);
            p = p / rs;
            float cs = p + __shfl_xor(p, 4);
            cs += __shfl_xor(cs, 8);
            p = p / cs;
        }
        if (lane < NC) pbuf[lane] = (lane < 16) ? p : vout;
    }
    __syncthreads();

    float hres[4][4], hpre[4], hpos[4];
#pragma unroll
    for (int i = 0; i < 16; ++i) hres[i >> 2][i & 3] = pbuf[i];
#pragma unroll
    for (int i = 0; i < 4; ++i) hpre[i] = pbuf[16 + i];
#pragma unroll
    for (int i = 0; i < 4; ++i) hpos[i] = pbuf[20 + i];

    const float4* __restrict__ Xr =
        reinterpret_cast<const float4*>(X + (size_t)row * K_DIM);
    float4* __restrict__ Or = reinterpret_cast<float4*>(out + (size_t)row * K_DIM);

#pragma unroll
    for (int q = 0; q < 2; ++q) {
        const int pos = t + q * 256;          // float4 index within a 2048-seg
        float4 xq[4];
#pragma unroll
        for (int i = 0; i < 4; ++i) xq[i] = Xr[i * (D_DIM / 4) + pos];

        float y[4];
#pragma unroll
        for (int e = 0; e < 4; ++e) {
            float s = 0.f;
#pragma unroll
            for (int i = 0; i < 4; ++i)
                s = fmaf(hpre[i], reinterpret_cast<const float*>(&xq[i])[e], s);
            y[e] = s;
        }

#pragma unroll
        for (int s = 0; s < 4; ++s) {
            float4 o;
            float* oe = reinterpret_cast<float*>(&o);
#pragma unroll
            for (int e = 0; e < 4; ++e) {
                float v = hpos[s] * y[e];
#pragma unroll
                for (int i = 0; i < 4; ++i)
                    v = fmaf(hres[s][i], reinterpret_cast<const float*>(&xq[i])[e], v);
                oe[e] = v;
            }
            Or[s * (D_DIM / 4) + pos] = o;
        }
    }
}

extern "C" void kernel_launch(void* const* d_in, const int* in_sizes, int n_in,
                              void* d_out, int out_size, void* d_ws, size_t ws_size,
                              hipStream_t stream) {
    const float* X  = (const float*)d_in[0];
    const float* W  = (const float*)d_in[1];
    const float* ab = (const float*)d_in[2];
    float* out = (float*)d_out;
    unsigned short* wfrag = (unsigned short*)d_ws;          // 524,288 B
    float* part = (float*)((char*)d_ws + 524288);           // + 6,291,456 B

    mhc_prepack_kernel<<<(K_DIM * N_W) / 256, 256, 0, stream>>>(W, wfrag);
    dim3 g1(M_ROWS / ROWS, KSPLIT);
    mhc_gemm_kernel<<<g1, THR, 0, stream>>>(X, wfrag, part);
    mhc_apply_kernel<<<M_ROWS, 256, 0, stream>>>(X, part, ab, out);
}

// Round 18
// 167.115 us; speedup vs baseline: 1.0043x; 1.0043x over previous
//
#include <hip/hip_runtime.h>
#include <math.h>
#include <stdint.h>

#define K_DIM 8192     // S*DIM
#define D_DIM 2048
#define M_ROWS 8192
#define N_W 32         // W columns (only 24 used in H)
#define NC 24
#define ROWS 16        // rows per block = one MFMA tile
#define THREADS 512    // 8 waves
#define WAVES 8
#define KPW 32         // ksteps per wave (8 waves x 32 = 256 = full K)
#define OUTER 8        // outer iters (ring period 4)

typedef short bf16x8 __attribute__((ext_vector_type(8)));
typedef float f32x4 __attribute__((ext_vector_type(4)));
union U32x4 { uint32_t u[4]; bf16x8 v; };

// wfrag (u16, W rne-bf16 hi-only): [ks(256)][tile(2)][lane(64)][e(8)] = 512 KB.
#define WFI(ks, tile) (((ks) * 2 + (tile)) * 64)   // bf16x8 units

// ---------------------------------------------------------------------------
// Kernel 0: prepack W -> rne bf16 B-fragments (once).
// k-map matches A-frag map: lane=((k&31)>>3)*16+(n&15), e=k&7 (same perm on
// both MFMA operands so it cancels; only C/D layout matters).
// ---------------------------------------------------------------------------
__global__ __launch_bounds__(256) void mhc_prepack_kernel(
    const float* __restrict__ W, unsigned short* __restrict__ wfrag)
{
    const int idx = blockIdx.x * 256 + threadIdx.x;   // 0 .. 262143
    const int k = idx >> 5, n = idx & 31;
    const float w = W[(size_t)k * N_W + n];
    const uint32_t u = __float_as_uint(w);
    const uint32_t r = u + 0x7FFFu + ((u >> 16) & 1u);   // round-nearest-even

    const int ks = k >> 5, kk = k & 31;
    const int lane = ((kk >> 3) << 4) | (n & 15);
    const int e = kk & 7;
    const int tile = n >> 4;
    wfrag[((size_t)WFI(ks, tile) + lane) * 8 + e] = (unsigned short)(r >> 16);
}

// ---------------------------------------------------------------------------
// FUSED kernel. Block = 512 thr (8 waves) owns 16 rows over FULL K.
//  Phase 1 (gemm): wave wv does ksteps [wv*32, wv*32+32): R13 inner loop
//    (static 4-deep X+B prefetch ring, hi/lo pack, 4 MFMA/kstep).
//    H = Xhi@W + Xlo@W (W rne-bf16, X exact split; absmax 0.031 validated).
//  Phase 2: LDS-reduce the 8 waves' partial H -> Hf[16][24].
//  Phase 3: waves 0-3: transform + 20-iter Sinkhorn, 4 rows/wave in
//    parallel (16-lane groups; verified shfl maps) -> pbuf[16][24].
//  Phase 4 (apply): all 512 thr sweep row r: 2KB-run loads of the block's
//    JUST-READ X rows (L2/L3-hot) + coalesced O stores.
// No ksplit, no atomics, no part buffer; 3 barriers total. Blocks in
// different phases overlap read-only and read+write HBM traffic (R14's
// concurrency effect by construction).
// C/D: D[row=(l>>4)*4+reg][col=l&15]  [HW-verified].
// ---------------------------------------------------------------------------
__global__ __launch_bounds__(THREADS, 4) void mhc_fused_kernel(
    const float* __restrict__ X, const unsigned short* __restrict__ wfrag,
    const float* __restrict__ ab, float* __restrict__ out)
{
    __shared__ float Hpart[WAVES][ROWS][NC];   // 12 KB
    __shared__ float Hf[ROWS * NC];            // 1.5 KB
    __shared__ float pbuf[ROWS * NC];          // 1.5 KB

    const int t = threadIdx.x;
    const int l = t & 63;
    const int wv = t >> 6;
    const int rowbase = blockIdx.x * ROWS;

    const float4* __restrict__ Xg = reinterpret_cast<const float4*>(X);
    const bf16x8* __restrict__ wf = reinterpret_cast<const bf16x8*>(wfrag);

    // ---- phase 1: MFMA gemm over this wave's k-range ----
    const int ks0 = wv * KPW;
    const int arow = rowbase + (l & 15);
    const size_t xbase = (size_t)arow * (K_DIM / 4) + ((l >> 4) << 1);

    f32x4 c0 = {0.f, 0.f, 0.f, 0.f};
    f32x4 c1 = {0.f, 0.f, 0.f, 0.f};

    float4 px[4][2];
    bf16x8 pb[4][2];
#pragma unroll
    for (int s = 0; s < 4; ++s) {
        px[s][0] = Xg[xbase + (size_t)(ks0 + s) * 8];
        px[s][1] = Xg[xbase + (size_t)(ks0 + s) * 8 + 1];
        pb[s][0] = wf[WFI(ks0 + s, 0) + l];
        pb[s][1] = wf[WFI(ks0 + s, 1) + l];
    }

    for (int c = 0; c < OUTER; ++c) {
#pragma unroll
        for (int s = 0; s < 4; ++s) {          // ring slot s: all-static idx
            const float4 xa = px[s][0];
            const float4 xb = px[s][1];
            const bf16x8 b0 = pb[s][0];
            const bf16x8 b1 = pb[s][1];

            if (c + 1 < OUTER) {               // reload slot for kstep+4
                const int ks = ks0 + (c + 1) * 4 + s;
                px[s][0] = Xg[xbase + (size_t)ks * 8];
                px[s][1] = Xg[xbase + (size_t)ks * 8 + 1];
                pb[s][0] = wf[WFI(ks, 0) + l];
                pb[s][1] = wf[WFI(ks, 1) + l];
            }

            float xs[8];
            xs[0] = xa.x; xs[1] = xa.y; xs[2] = xa.z; xs[3] = xa.w;
            xs[4] = xb.x; xs[5] = xb.y; xs[6] = xb.z; xs[7] = xb.w;

            U32x4 ah, al;
#pragma unroll
            for (int p = 0; p < 4; ++p) {
                const uint32_t u0 = __float_as_uint(xs[2 * p]);
                const uint32_t u1 = __float_as_uint(xs[2 * p + 1]);
                const float h0 = __uint_as_float(u0 & 0xFFFF0000u);
                const float h1 = __uint_as_float(u1 & 0xFFFF0000u);
                const uint32_t r0 = __float_as_uint(xs[2 * p] - h0);
                const uint32_t r1 = __float_as_uint(xs[2 * p + 1] - h1);
                ah.u[p] = (u1 & 0xFFFF0000u) | (u0 >> 16);
                al.u[p] = (r1 & 0xFFFF0000u) | (r0 >> 16);
            }

            c0 = __builtin_amdgcn_mfma_f32_16x16x32_bf16(ah.v, b0, c0, 0, 0, 0);
            c0 = __builtin_amdgcn_mfma_f32_16x16x32_bf16(al.v, b0, c0, 0, 0, 0);
            c1 = __builtin_amdgcn_mfma_f32_16x16x32_bf16(ah.v, b1, c1, 0, 0, 0);
            c1 = __builtin_amdgcn_mfma_f32_16x16x32_bf16(al.v, b1, c1, 0, 0, 0);
        }
    }

    // ---- stash partials: D[row=(l>>4)*4+r][col=l&15] ----
#pragma unroll
    for (int r = 0; r < 4; ++r)
        Hpart[wv][((l >> 4) << 2) + r][l & 15] = c0[r];
    if ((l & 15) < 8) {
#pragma unroll
        for (int r = 0; r < 4; ++r)
            Hpart[wv][((l >> 4) << 2) + r][16 + (l & 15)] = c1[r];
    }
    __syncthreads();

    // ---- phase 2: reduce 8 partials ----
    if (t < ROWS * NC) {
        float h = 0.f;
#pragma unroll
        for (int w = 0; w < WAVES; ++w)
            h += Hpart[w][t / NC][t % NC];
        Hf[t] = h;
    }
    __syncthreads();

    // ---- phase 3: transform + sinkhorn (waves 0-3, 4 rows each) ----
    if (wv < 4) {
        const int row16 = wv * 4 + (l >> 4);   // 0..15
        const int idx = l & 15;
        float p = __expf(fmaf(ab[24], Hf[row16 * NC + idx], ab[idx]));

        if (l < 32) {
            const int rr = wv * 4 + (l >> 3);
            const int ci = 16 + (l & 7);
            const float sc = (ci < 20) ? ab[25] : ab[26];
            pbuf[rr * NC + ci] =
                fmaf(sc, 1.f / (1.f + __expf(-Hf[rr * NC + ci])), ab[ci]);
        }

        // Sinkhorn on 16-lane groups: idx = s*4+i; row-sum xor 1,2; col xor 4,8
        for (int it = 0; it < 20; ++it) {
            float rs = p + __shfl_xor(p, 1);
            rs += __shfl_xor(rs, 2);
            p = p / rs;
            float cs = p + __shfl_xor(p, 4);
            cs += __shfl_xor(cs, 8);
            p = p / cs;
        }
        pbuf[row16 * NC + idx] = p;
    }
    __syncthreads();

    // ---- phase 4: apply, all 512 threads per row (2KB runs, X L2/L3-hot) --
    float4* __restrict__ Og = reinterpret_cast<float4*>(out);
    for (int r = 0; r < ROWS; ++r) {
        const float* pr = &pbuf[r * NC];
        float hre[4][4], hpr[4], hpo[4];
#pragma unroll
        for (int q = 0; q < 16; ++q) hre[q >> 2][q & 3] = pr[q];
#pragma unroll
        for (int q = 0; q < 4; ++q) hpr[q] = pr[16 + q];
#pragma unroll
        for (int q = 0; q < 4; ++q) hpo[q] = pr[20 + q];

        const size_t rb4 = (size_t)(rowbase + r) * (K_DIM / 4);
        float4 xq[4];
#pragma unroll
        for (int i = 0; i < 4; ++i) xq[i] = Xg[rb4 + i * 512 + t];

        float y[4];
#pragma unroll
        for (int e = 0; e < 4; ++e) {
            float v = 0.f;
#pragma unroll
            for (int i = 0; i < 4; ++i)
                v = fmaf(hpr[i], reinterpret_cast<const float*>(&xq[i])[e], v);
            y[e] = v;
        }

#pragma unroll
        for (int s = 0; s < 4; ++s) {
            float4 o;
            float* oe = reinterpret_cast<float*>(&o);
#pragma unroll
            for (int e = 0; e < 4; ++e) {
                float v = hpo[s] * y[e];
#pragma unroll
                for (int i = 0; i < 4; ++i)
                    v = fmaf(hre[s][i],
                             reinterpret_cast<const float*>(&xq[i])[e], v);
                oe[e] = v;
            }
            Og[rb4 + s * 512 + t] = o;
        }
    }
}

extern "C" void kernel_launch(void* const* d_in, const int* in_sizes, int n_in,
                              void* d_out, int out_size, void* d_ws, size_t ws_size,
                              hipStream_t stream) {
    const float* X  = (const float*)d_in[0];
    const float* W  = (const float*)d_in[1];
    const float* ab = (const float*)d_in[2];
    float* out = (float*)d_out;
    unsigned short* wfrag = (unsigned short*)d_ws;   // 524,288 B

    mhc_prepack_kernel<<<(K_DIM * N_W) / 256, 256, 0, stream>>>(W, wfrag);
    mhc_fused_kernel<<<M_ROWS / ROWS, THREADS, 0, stream>>>(X, wfrag, ab, out);
}